// Round 21
// baseline (225.352 us; speedup 1.0000x reference)
//
#include <hip/hip_runtime.h>

// ---------------- problem constants ----------------
constexpr int BATCH = 4;
constexpr int HS    = 64;     // H
constexpr int WSZ   = 64;     // W
constexpr int LSEQ  = 4096;   // L = H*W
constexpr int DM    = 96;     // d_model
constexpr int DI    = 192;    // d_inner
constexpr int NS    = 16;     // d_state
constexpr int RK    = 6;      // dt_rank
constexpr int KD    = 4;      // scan directions
constexpr int NCH   = 128;    // chunks along L
constexpr int CLEN  = 32;     // chunk length
constexpr int GRP   = 16;     // pre-pass group size
constexpr int XDS   = 160;    // packed xdbl row: 4 * [B(16) C(16) dt(6) pad(2)]
constexpr int GCH   = 16;     // combine groups
constexpr int GLEN  = NCH / GCH;  // 8 chunks per group

typedef float v2f __attribute__((ext_vector_type(2)));

__device__ __forceinline__ v2f mkv2(float a, float b) { v2f r; r.x = a; r.y = b; return r; }

// packed fp32 (pure-register asm; no memory hazards)
__device__ __forceinline__ v2f pk_fma(v2f a, v2f b, v2f c) {
  v2f d;
  asm("v_pk_fma_f32 %0, %1, %2, %3" : "=v"(d) : "v"(a), "v"(b), "v"(c));
  return d;
}
__device__ __forceinline__ v2f pk_mul(v2f a, v2f b) {
  v2f d;
  asm("v_pk_mul_f32 %0, %1, %2" : "=v"(d) : "v"(a), "v"(b));
  return d;
}

// scan index l -> spatial position p (row-major h*64+w), per direction
__device__ __forceinline__ int pos_of(int k, int l) {
  switch (k & 3) {
    case 0: return l;
    case 1: return ((l & 63) << 6) | (l >> 6);
    case 2: return LSEQ - 1 - l;
    default: { int lp = LSEQ - 1 - l; return ((lp & 63) << 6) | (lp >> 6); }
  }
}

// within a chunk (l0 mod 32 == 0), pos_of(k, l0+j) = pos_of(k,l0) + j*step
__device__ __forceinline__ int pos_step(int k) {
  switch (k & 3) {
    case 0: return 1;
    case 1: return 64;
    case 2: return -1;
    default: return -64;
  }
}

__device__ __forceinline__ float softplus_f(float s) {
  return (s > 20.f) ? s : __logf(1.f + __expf(s));
}

// geo check on A_logs directly: Alog[n] == Alog[0] + ln(n+1)
__device__ __forceinline__ bool geo_check(const float* Al) {
  const float lntab[16] = {0.f, 0.6931472f, 1.0986123f, 1.3862944f, 1.6094379f,
                           1.7917595f, 1.9459101f, 2.0794415f, 2.1972246f, 2.3025851f,
                           2.3978953f, 2.4849066f, 2.5649494f, 2.6390573f, 2.7080502f,
                           2.7725887f};
  bool g = true;
  #pragma unroll
  for (int n = 0; n < NS; ++n)
    g = g && (fabsf(Al[n] - Al[0] - lntab[n]) <= 2e-3f);
  return g;
}

// packed dt6: s = bsv + w.t
__device__ __forceinline__ float dt6p(const v2f* w2, float bsv, float4 t0, float4 t1) {
  v2f acc = pk_mul(w2[0], mkv2(t0.x, t0.y));
  acc = pk_fma(w2[1], mkv2(t0.z, t0.w), acc);
  acc = pk_fma(w2[2], mkv2(t1.x, t1.y), acc);
  return bsv + acc.x + acc.y;
}

// packed powers, log-depth: pw2[q] = {e^(2q+1), e^(2q+2)}, q=0..7 (depth 4)
__device__ __forceinline__ void pw8p(float e, v2f* pw2) {
  float e2 = e * e, e4 = e2 * e2, e8 = e4 * e4;
  v2f e2v = mkv2(e2, e2), e4v = mkv2(e4, e4), e8v = mkv2(e8, e8);
  pw2[0] = mkv2(e, e2);
  pw2[1] = pk_mul(pw2[0], e2v);   // e3 e4
  pw2[2] = pk_mul(pw2[0], e4v);   // e5 e6
  pw2[3] = pk_mul(pw2[1], e4v);   // e7 e8
  pw2[4] = pk_mul(pw2[0], e8v);   // e9 e10
  pw2[5] = pk_mul(pw2[1], e8v);   // e11 e12
  pw2[6] = pk_mul(pw2[2], e8v);   // e13 e14
  pw2[7] = pk_mul(pw2[3], e8v);   // e15 e16
}

__device__ __forceinline__ float dt6(const float* w, float bsv, float4 t0, float4 t1) {
  return bsv + w[0]*t0.x + w[1]*t0.y + w[2]*t0.z + w[3]*t0.w + w[4]*t1.x + w[5]*t1.y;
}

// ---------------- merged weight prep + per-(k,d) scan constants ------------------
__launch_bounds__(256)
__global__ void prep_weights(const float* __restrict__ xw, const float* __restrict__ ipw,
                             const float* __restrict__ opw, const float* __restrict__ Alog,
                             const float* __restrict__ dtw, const float* __restrict__ dtb,
                             float* __restrict__ WcatT, float* __restrict__ inpT,
                             float* __restrict__ outpT, float4* __restrict__ ctab,
                             int* __restrict__ gflag) {
  int idx = blockIdx.x * 256 + threadIdx.x;
  if (idx < DI * XDS) {                          // WcatT
    int col = idx / XDS, j = idx % XDS;
    int k = j / 40, jj = j % 40;
    float v = 0.f;
    int src = -1;
    if (jj < 16)      src = k * 38 + 6 + jj;
    else if (jj < 32) src = k * 38 + 22 + (jj - 16);
    else if (jj < 38) src = k * 38 + (jj - 32);
    if (src >= 0) v = xw[(size_t)src * DI + col];
    WcatT[idx] = v;
    return;
  }
  idx -= DI * XDS;
  if (idx < 2 * DI * DM) {                       // inpT[c][r] = ipw[r][c]
    int r = idx / DM, c = idx % DM;
    inpT[(size_t)c * (2 * DI) + r] = ipw[idx];
    return;
  }
  idx -= 2 * DI * DM;
  if (idx < DM * DI) {                           // outpT[c][r] = opw[r][c]
    int r = idx / DI, c = idx % DI;
    outpT[(size_t)c * DM + r] = opw[idx];
    return;
  }
  idx -= DM * DI;
  if (idx < KD * DI) {                           // scan constants
    float Al[NS];
    #pragma unroll
    for (int n = 0; n < NS; ++n) Al[n] = Alog[(size_t)idx * NS + n];
    gflag[idx] = geo_check(Al) ? 1 : 0;
    float An0 = -__expf(Al[0]);
    float bsv = dtb[idx];
    const float* wp = &dtw[(size_t)idx * RK];
    ctab[idx * 2 + 0] = make_float4(An0, bsv, wp[0], wp[1]);
    ctab[idx * 2 + 1] = make_float4(wp[2], wp[3], wp[4], wp[5]);
  }
}

// ---------------- GEMM: C[M,NN] = A[M,KK] * BT[KK,NN]   (BT pre-transposed) ------
template <int NN, int KK, int TM, int KT>
__launch_bounds__(256)
__global__ void gemm_nt(const float* __restrict__ A, const float* __restrict__ BT,
                        float* __restrict__ C, int M) {
  constexpr int TN  = 64;
  constexpr int RPT = TM / 16;
  constexpr int SA  = KT + 4;
  constexpr int KQ  = KT / 4;
  __shared__ float As[TM][SA];
  __shared__ float Bs[KT][TN];
  const int t = threadIdx.x;
  const int row0 = blockIdx.y * TM;
  const int col0 = blockIdx.x * TN;
  const int tc = t & 15;
  const int tr = t >> 4;

  float acc[RPT][4];
  #pragma unroll
  for (int i = 0; i < RPT; ++i)
    { acc[i][0]=0.f; acc[i][1]=0.f; acc[i][2]=0.f; acc[i][3]=0.f; }

  for (int k0 = 0; k0 < KK; k0 += KT) {
    #pragma unroll 1
    for (int idx = t; idx < TM * KQ; idx += 256) {
      int r = idx / KQ, kq = idx % KQ;
      *(float4*)&As[r][kq * 4] =
          *(const float4*)&A[(size_t)(row0 + r) * KK + k0 + kq * 4];
    }
    #pragma unroll 1
    for (int idx = t; idx < KT * 16; idx += 256) {
      int kk = idx >> 4, cq = idx & 15;
      int col = col0 + cq * 4;
      float4 v = make_float4(0.f, 0.f, 0.f, 0.f);
      if (col < NN) v = *(const float4*)&BT[(size_t)(k0 + kk) * NN + col];
      *(float4*)&Bs[kk][cq * 4] = v;
    }
    __syncthreads();
    #pragma unroll 4
    for (int kk = 0; kk < KT; ++kk) {
      float4 bv = *(const float4*)&Bs[kk][tc * 4];
      #pragma unroll
      for (int i = 0; i < RPT; ++i) {
        float a = As[tr * RPT + i][kk];
        acc[i][0] += a * bv.x; acc[i][1] += a * bv.y;
        acc[i][2] += a * bv.z; acc[i][3] += a * bv.w;
      }
    }
    __syncthreads();
  }
  int c = col0 + tc * 4;
  if (c < NN) {
    #pragma unroll
    for (int i = 0; i < RPT; ++i) {
      size_t r0 = (size_t)(row0 + tr * RPT + i) * NN + c;
      *(float4*)&C[r0] = make_float4(acc[i][0], acc[i][1], acc[i][2], acc[i][3]);
    }
  }
}

// ---------------- depthwise 3x3 conv + bias + SiLU ----------------
__launch_bounds__(256)
__global__ void conv_silu(const float* __restrict__ xz, const float* __restrict__ cw,
                          const float* __restrict__ cb, float* __restrict__ xc) {
  int idx = blockIdx.x * 256 + threadIdx.x;
  int d = idx % DI;
  int p = (idx / DI) % LSEQ;
  int b = idx / (DI * LSEQ);
  int h = p >> 6, w = p & 63;
  float acc = cb[d];
  #pragma unroll
  for (int kh = 0; kh < 3; ++kh) {
    int hh = h + kh - 1;
    if ((unsigned)hh >= (unsigned)HS) continue;
    #pragma unroll
    for (int kw = 0; kw < 3; ++kw) {
      int ww = w + kw - 1;
      if ((unsigned)ww >= (unsigned)WSZ) continue;
      acc += xz[((size_t)b * LSEQ + (hh << 6) + ww) * (2 * DI) + d] * cw[d * 9 + kh * 3 + kw];
    }
  }
  xc[idx] = acc / (1.f + __expf(-acc));
}

// ---- scan phase 1: parallel pre-pass + short serial pass (packed fp32) ----------
__launch_bounds__(192)
__global__ void scan_phase1(const float* __restrict__ xc, const float* __restrict__ xdbl,
                            const float4* __restrict__ ctab, const int* __restrict__ gflag,
                            const float* __restrict__ Alog,
                            float* __restrict__ hN, float* __restrict__ sumdB,
                            float* __restrict__ ypl) {
  const int d = threadIdx.x;
  const int ch = blockIdx.x, k = blockIdx.y, b = blockIdx.z;
  const int bk = b * KD + k;
  const int kd = k * DI + d;
  __shared__ float4 Bsh[CLEN * 10];         // per pos: B(0..3) C(4..7) dt(8,9)
  #pragma unroll 1
  for (int idx = d; idx < CLEN * 10; idx += 192) {
    int j = idx / 10, q = idx % 10;
    int p = pos_of(k, ch * CLEN + j);
    Bsh[idx] = *(const float4*)&xdbl[(size_t)(b * LSEQ + p) * XDS + k * 40 + q * 4];
  }
  const float4 c0 = ctab[kd * 2 + 0];
  const float4 c1 = ctab[kd * 2 + 1];
  const float An0 = c0.x, bsv = c0.y;
  v2f w2[3];
  w2[0] = mkv2(c0.z, c0.w); w2[1] = mkv2(c1.x, c1.y); w2[2] = mkv2(c1.z, c1.w);
  const bool geo = gflag[kd] != 0;
  __syncthreads();

  float sumd = 0.f;
  const int l0 = ch * CLEN;
  const int p0 = pos_of(k, l0);
  const long pstride = (long)pos_step(k) * DI;
  const float* xcp = xc + ((size_t)b * LSEQ + p0) * DI + d;
  float* youtp = ypl + ((size_t)bk * LSEQ + p0) * DI + d;
  v2f h2[8];
  #pragma unroll
  for (int q = 0; q < 8; ++q) h2[q] = mkv2(0.f, 0.f);
  if (geo) {
    #pragma unroll
    for (int grp = 0; grp < CLEN / GRP; ++grp) {
      float e_[GRP], du_[GRP];
      // parallel pre-pass: independent across jj (trans pipelined, xc overlapped)
      #pragma unroll
      for (int jj = 0; jj < GRP; ++jj) {
        const int j = grp * GRP + jj;
        float4 t0 = Bsh[j * 10 + 8], t1 = Bsh[j * 10 + 9];
        float dl = softplus_f(dt6p(w2, bsv, t0, t1));
        sumd += dl;
        du_[jj] = dl * xcp[(long)j * pstride];
        e_[jj] = __expf(dl * An0);
      }
      // serial pass: short chain (pw tree + pk_fma)
      #pragma unroll
      for (int jj = 0; jj < GRP; ++jj) {
        const int j = grp * GRP + jj;
        v2f pw2[8];
        pw8p(e_[jj], pw2);
        v2f du2 = mkv2(du_[jj], du_[jj]);
        v2f y2 = mkv2(0.f, 0.f);
        #pragma unroll
        for (int q = 0; q < 4; ++q) {
          float4 v  = Bsh[j * 10 + q];
          float4 c4 = Bsh[j * 10 + 4 + q];
          h2[2*q]   = pk_fma(pw2[2*q],   h2[2*q],   pk_mul(du2, mkv2(v.x, v.y)));
          y2 = pk_fma(h2[2*q],   mkv2(c4.x, c4.y), y2);
          h2[2*q+1] = pk_fma(pw2[2*q+1], h2[2*q+1], pk_mul(du2, mkv2(v.z, v.w)));
          y2 = pk_fma(h2[2*q+1], mkv2(c4.z, c4.w), y2);
        }
        youtp[(long)j * pstride] = y2.x + y2.y;
      }
    }
  } else {
    float w[RK] = {c0.z, c0.w, c1.x, c1.y, c1.z, c1.w};
    float An[NS];
    #pragma unroll
    for (int n = 0; n < NS; ++n) An[n] = -__expf(Alog[(size_t)kd * NS + n]);
    float h[NS];
    #pragma unroll
    for (int n = 0; n < NS; ++n) h[n] = 0.f;
    #pragma unroll 1
    for (int j = 0; j < CLEN; ++j) {
      float4 t0 = Bsh[j * 10 + 8], t1 = Bsh[j * 10 + 9];
      float dl = softplus_f(dt6(w, bsv, t0, t1));
      float du = dl * xcp[(long)j * pstride];
      float y = 0.f;
      #pragma unroll
      for (int q = 0; q < 4; ++q) {
        float4 v  = Bsh[j * 10 + q];
        float4 c4 = Bsh[j * 10 + 4 + q];
        h[q*4+0] = __expf(dl * An[q*4+0]) * h[q*4+0] + du * v.x; y += h[q*4+0] * c4.x;
        h[q*4+1] = __expf(dl * An[q*4+1]) * h[q*4+1] + du * v.y; y += h[q*4+1] * c4.y;
        h[q*4+2] = __expf(dl * An[q*4+2]) * h[q*4+2] + du * v.z; y += h[q*4+2] * c4.z;
        h[q*4+3] = __expf(dl * An[q*4+3]) * h[q*4+3] + du * v.w; y += h[q*4+3] * c4.w;
      }
      sumd += dl;
      youtp[(long)j * pstride] = y;
    }
    #pragma unroll
    for (int q = 0; q < 8; ++q) h2[q] = mkv2(h[2*q], h[2*q+1]);
  }
  const size_t o = ((size_t)bk * NCH + ch) * DI + d;
  float4* Hp = (float4*)&hN[o * NS];
  #pragma unroll
  for (int q = 0; q < 4; ++q)
    Hp[q] = make_float4(h2[2*q].x, h2[2*q].y, h2[2*q+1].x, h2[2*q+1].y);
  sumdB[o] = sumd;
}

// ---- fused hierarchical combine: one block per (bk,d): 16 n x 16 groups --------
__launch_bounds__(256)
__global__ void combine_all(float* __restrict__ hN, const float* __restrict__ sumdB,
                            const float* __restrict__ Alog) {
  const int t = threadIdx.x;
  const int n = t & 15;
  const int g = t >> 4;
  const int d = blockIdx.x;
  const int k = blockIdx.y, b = blockIdx.z;
  const int bk = b * KD + k;
  const float An = -__expf(Alog[((size_t)k * DI + d) * NS + n]);
  __shared__ float Wl[GCH][NS], Tl[GCH][NS], Hl[GCH][NS];

  float wreg[GLEN], hreg[GLEN];
  float W = 1.f, T = 0.f;
  #pragma unroll
  for (int j = 0; j < GLEN; ++j) {
    const int c = g * GLEN + j;
    const size_t o = ((size_t)bk * NCH + c) * DI + d;
    float wv = __expf(An * sumdB[o]);
    float hv = hN[o * NS + n];
    wreg[j] = wv; hreg[j] = hv;
    T = hv + wv * T;
    W *= wv;
  }
  Wl[g][n] = W; Tl[g][n] = T;
  __syncthreads();
  if (g == 0) {
    float H = 0.f;
    #pragma unroll
    for (int g2 = 0; g2 < GCH; ++g2) {
      float Wv = Wl[g2][n], Tv = Tl[g2][n];
      Hl[g2][n] = H;
      H = Tv + Wv * H;
    }
  }
  __syncthreads();
  float e = Hl[g][n];
  #pragma unroll
  for (int j = 0; j < GLEN; ++j) {
    const int c = g * GLEN + j;
    const size_t o = ((size_t)bk * NCH + c) * DI + d;
    hN[o * NS + n] = e;
    e = hreg[j] + wreg[j] * e;
  }
}

// ---- scan correction: fully-parallel phases (packed fp32) ----------------------
__launch_bounds__(192)
__global__ void scan_corr(const float* __restrict__ xdbl, const float4* __restrict__ ctab,
                          const int* __restrict__ gflag, const float* __restrict__ Alog,
                          const float* __restrict__ hin, float* __restrict__ ypl) {
  const int d = threadIdx.x;
  const int ch = blockIdx.x + 1;            // ch=0 has zero entry state
  const int k = blockIdx.y, b = blockIdx.z;
  const int bk = b * KD + k;
  const int kd = k * DI + d;
  __shared__ float4 Bsh[CLEN * 6];          // per pos: C(q4..7) dt(q8,q9)
  {
    int idx = d;                            // CLEN*6 == 192
    int j = idx / 6, q = idx % 6;
    int p = pos_of(k, ch * CLEN + j);
    Bsh[idx] = *(const float4*)&xdbl[(size_t)(b * LSEQ + p) * XDS + k * 40 + (q + 4) * 4];
  }
  const float4 c0 = ctab[kd * 2 + 0];
  const float4 c1 = ctab[kd * 2 + 1];
  const float An0 = c0.x, bsv = c0.y;
  v2f w2[3];
  w2[0] = mkv2(c0.z, c0.w); w2[1] = mkv2(c1.x, c1.y); w2[2] = mkv2(c1.z, c1.w);
  const bool geo = gflag[kd] != 0;

  v2f g2[8];                                // entry state h0
  {
    const size_t o = ((size_t)bk * NCH + ch) * DI + d;
    const float4* Hp = (const float4*)&hin[o * NS];
    #pragma unroll
    for (int q = 0; q < 4; ++q) {
      float4 v = Hp[q];
      g2[2*q]   = mkv2(v.x, v.y);
      g2[2*q+1] = mkv2(v.z, v.w);
    }
  }
  __syncthreads();
  const int l0 = ch * CLEN;
  const int p0 = pos_of(k, l0);
  const long pstride = (long)pos_step(k) * DI;
  float* youtp = ypl + ((size_t)bk * LSEQ + p0) * DI + d;
  float cum = 0.f;
  if (geo) {
    #pragma unroll
    for (int grp = 0; grp < CLEN / GRP; ++grp) {
      float e_[GRP];
      // phase A: independent softplus
      #pragma unroll
      for (int jj = 0; jj < GRP; ++jj) {
        const int j = grp * GRP + jj;
        float4 t0 = Bsh[j * 6 + 4], t1 = Bsh[j * 6 + 5];
        e_[jj] = softplus_f(dt6p(w2, bsv, t0, t1));
      }
      // phase B: scalar prefix (1-cyc adds), in place
      #pragma unroll
      for (int jj = 0; jj < GRP; ++jj) { cum += e_[jj]; e_[jj] = cum; }
      // phase C: independent exp
      #pragma unroll
      for (int jj = 0; jj < GRP; ++jj) e_[jj] = __expf(e_[jj] * An0);
      // phase D: independent dots + RMW
      #pragma unroll
      for (int jj = 0; jj < GRP; ++jj) {
        const int j = grp * GRP + jj;
        v2f pw2[8];
        pw8p(e_[jj], pw2);
        v2f y2 = mkv2(0.f, 0.f);
        #pragma unroll
        for (int q = 0; q < 4; ++q) {
          float4 c4 = Bsh[j * 6 + q];
          y2 = pk_fma(pk_mul(pw2[2*q],   g2[2*q]),   mkv2(c4.x, c4.y), y2);
          y2 = pk_fma(pk_mul(pw2[2*q+1], g2[2*q+1]), mkv2(c4.z, c4.w), y2);
        }
        youtp[(long)j * pstride] += y2.x + y2.y;
      }
    }
  } else {
    float w[RK] = {c0.z, c0.w, c1.x, c1.y, c1.z, c1.w};
    float An[NS];
    #pragma unroll
    for (int n = 0; n < NS; ++n) An[n] = -__expf(Alog[(size_t)kd * NS + n]);
    #pragma unroll 1
    for (int j = 0; j < CLEN; ++j) {
      float4 t0 = Bsh[j * 6 + 4], t1 = Bsh[j * 6 + 5];
      cum += softplus_f(dt6(w, bsv, t0, t1));
      float y = 0.f;
      #pragma unroll
      for (int q = 0; q < 4; ++q) {
        float4 c4 = Bsh[j * 6 + q];
        y += (__expf(An[q*4+0] * cum) * g2[2*q].x)   * c4.x;
        y += (__expf(An[q*4+1] * cum) * g2[2*q].y)   * c4.y;
        y += (__expf(An[q*4+2] * cum) * g2[2*q+1].x) * c4.z;
        y += (__expf(An[q*4+3] * cum) * g2[2*q+1].y) * c4.w;
      }
      youtp[(long)j * pstride] += y;
    }
  }
}

// -------- 4-plane merge (Ds term) + LayerNorm + SiLU gate ----------------
__launch_bounds__(192)
__global__ void fuse_ln(const float* __restrict__ ypl, const float* __restrict__ xc,
                        const float* __restrict__ Ds, const float* __restrict__ xz,
                        const float* __restrict__ lnw, const float* __restrict__ lnb,
                        float* __restrict__ ymul) {
  const int row = blockIdx.x;           // b*L + p
  const int b = row >> 12;
  const size_t pd = (size_t)row * DI + threadIdx.x;
  const int d = threadIdx.x;
  constexpr size_t PL = (size_t)LSEQ * DI;
  float u = xc[pd];
  float sDs = Ds[d] + Ds[DI + d] + Ds[2 * DI + d] + Ds[3 * DI + d];
  const size_t base = (size_t)(b * KD) * PL + pd - (size_t)b * PL;
  float y = ypl[base] + ypl[base + PL] + ypl[base + 2 * PL] + ypl[base + 3 * PL] + sDs * u;
  float s1 = y, s2 = y * y;
  #pragma unroll
  for (int off = 32; off; off >>= 1) {
    s1 += __shfl_xor(s1, off);
    s2 += __shfl_xor(s2, off);
  }
  __shared__ float r1[3], r2[3];
  int wid = d >> 6;
  if ((d & 63) == 0) { r1[wid] = s1; r2[wid] = s2; }
  __syncthreads();
  float S1 = r1[0] + r1[1] + r1[2];
  float S2 = r2[0] + r2[1] + r2[2];
  float mu = S1 * (1.f / DI);
  float var = S2 * (1.f / DI) - mu * mu;
  float yn = (y - mu) * rsqrtf(var + 1e-5f) * lnw[d] + lnb[d];
  float zv = xz[(size_t)row * (2 * DI) + DI + d];
  float g = zv / (1.f + __expf(-zv));
  ymul[pd] = yn * g;
}

// ---------------- launcher ----------------
extern "C" void kernel_launch(void* const* d_in, const int* in_sizes, int n_in,
                              void* d_out, int out_size, void* d_ws, size_t ws_size,
                              hipStream_t stream) {
  (void)in_sizes; (void)n_in; (void)out_size; (void)ws_size;
  const float* x          = (const float*)d_in[0];
  const float* in_proj_w  = (const float*)d_in[1];
  const float* conv_w     = (const float*)d_in[2];
  const float* conv_b     = (const float*)d_in[3];
  const float* x_proj_w   = (const float*)d_in[4];
  const float* dt_w       = (const float*)d_in[5];
  const float* dt_b       = (const float*)d_in[6];
  const float* A_logs     = (const float*)d_in[7];
  const float* Ds         = (const float*)d_in[8];
  const float* ln_w       = (const float*)d_in[9];
  const float* ln_b       = (const float*)d_in[10];
  const float* out_proj_w = (const float*)d_in[11];
  float* out = (float*)d_out;
  float* ws  = (float*)d_ws;

  constexpr size_t SZ_XZ    = (size_t)BATCH * LSEQ * 2 * DI;
  constexpr size_t SZ_XC    = (size_t)BATCH * LSEQ * DI;
  constexpr size_t SZ_XD    = (size_t)BATCH * LSEQ * XDS;
  constexpr size_t SZ_HN    = (size_t)BATCH * KD * NCH * DI * NS;   // 25 MB
  constexpr size_t SZ_SUMD  = (size_t)BATCH * KD * NCH * DI;
  constexpr size_t SZ_YPL   = (size_t)BATCH * KD * LSEQ * DI;

  float* xz    = ws;
  float* xc    = xz + SZ_XZ;
  float* xdbl  = xc + SZ_XC;
  float* hN    = xdbl + SZ_XD;
  float* sumd  = hN + SZ_HN;
  float* ypl   = sumd + SZ_SUMD;
  float* WcatT = ypl + SZ_YPL;
  float* inpT  = WcatT + (size_t)DI * XDS;
  float* outpT = inpT + (size_t)DM * 2 * DI;
  float4* ctab = (float4*)(outpT + (size_t)DI * DM);
  int*   gflag = (int*)(ctab + (size_t)KD * DI * 2);
  float* ymul  = hN;    // hN dead after scan_corr; reuse for LN output

  const int M = BATCH * LSEQ;  // 16384
  const int PREP = DI * XDS + 2 * DI * DM + DM * DI + KD * DI;

  // 0. weight prep (merged, + scan constants table)
  prep_weights<<<(PREP + 255) / 256, 256, 0, stream>>>(x_proj_w, in_proj_w, out_proj_w,
                                                       A_logs, dt_w, dt_b,
                                                       WcatT, inpT, outpT, ctab, gflag);
  // 1. in_proj
  gemm_nt<2 * DI, DM, 64, 96><<<dim3(6, M / 64), 256, 0, stream>>>(x, inpT, xz, M);
  // 2. depthwise conv + SiLU -> xc
  conv_silu<<<(BATCH * LSEQ * DI) / 256, 256, 0, stream>>>(xz, conv_w, conv_b, xc);
  // 3. x_proj all directions: xdbl[M,160]
  gemm_nt<XDS, DI, 64, 96><<<dim3(3, M / 64), 256, 0, stream>>>(xc, WcatT, xdbl, M);
  // 4. scan phase 1: pre-pass + short serial pass
  scan_phase1<<<dim3(NCH, KD, BATCH), 192, 0, stream>>>(xc, xdbl, ctab, gflag, A_logs,
                                                        hN, sumd, ypl);
  // 5. fused hierarchical combine (hN -> entry states, in place)
  combine_all<<<dim3(DI, KD, BATCH), 256, 0, stream>>>(hN, sumd, A_logs);
  // 6. correction: phased-parallel
  scan_corr<<<dim3(NCH - 1, KD, BATCH), 192, 0, stream>>>(xdbl, ctab, gflag, A_logs,
                                                          hN, ypl);
  // 7. merge 4 planes + LN + gate -> ymul (aliases hN)
  fuse_ln<<<M, DI, 0, stream>>>(ypl, xc, Ds, xz, ln_w, ln_b, ymul);
  // 8. out_proj
  gemm_nt<DM, DI, 64, 96><<<dim3(2, M / 64), 256, 0, stream>>>(ymul, outpT, out, M);
}

// Round 22
// 201.560 us; speedup vs baseline: 1.1180x; 1.1180x over previous
//
#include <hip/hip_runtime.h>

// ---------------- problem constants ----------------
constexpr int BATCH = 4;
constexpr int HS    = 64;     // H
constexpr int WSZ   = 64;     // W
constexpr int LSEQ  = 4096;   // L = H*W
constexpr int DM    = 96;     // d_model
constexpr int DI    = 192;    // d_inner
constexpr int NS    = 16;     // d_state
constexpr int RK    = 6;      // dt_rank
constexpr int KD    = 4;      // scan directions
constexpr int NCH   = 128;    // chunks along L
constexpr int CLEN  = 32;     // chunk length
constexpr int XDS   = 160;    // packed xdbl row: 4 * [B(16) C(16) dt(6) pad(2)]
constexpr int GCH   = 16;     // combine groups
constexpr int GLEN  = NCH / GCH;  // 8 chunks per group

typedef float v2f __attribute__((ext_vector_type(2)));

__device__ __forceinline__ v2f mkv2(float a, float b) { v2f r; r.x = a; r.y = b; return r; }

// packed fp32 (pure-register asm; no memory hazards)
__device__ __forceinline__ v2f pk_fma(v2f a, v2f b, v2f c) {
  v2f d;
  asm("v_pk_fma_f32 %0, %1, %2, %3" : "=v"(d) : "v"(a), "v"(b), "v"(c));
  return d;
}
__device__ __forceinline__ v2f pk_mul(v2f a, v2f b) {
  v2f d;
  asm("v_pk_mul_f32 %0, %1, %2" : "=v"(d) : "v"(a), "v"(b));
  return d;
}

// scan index l -> spatial position p (row-major h*64+w), per direction
__device__ __forceinline__ int pos_of(int k, int l) {
  switch (k & 3) {
    case 0: return l;
    case 1: return ((l & 63) << 6) | (l >> 6);
    case 2: return LSEQ - 1 - l;
    default: { int lp = LSEQ - 1 - l; return ((lp & 63) << 6) | (lp >> 6); }
  }
}

// within a chunk (l0 mod 32 == 0), pos_of(k, l0+j) = pos_of(k,l0) + j*step
__device__ __forceinline__ int pos_step(int k) {
  switch (k & 3) {
    case 0: return 1;
    case 1: return 64;
    case 2: return -1;
    default: return -64;
  }
}

__device__ __forceinline__ float softplus_f(float s) {
  return (s > 20.f) ? s : __logf(1.f + __expf(s));
}

// geo check on A_logs directly: Alog[n] == Alog[0] + ln(n+1)
__device__ __forceinline__ bool geo_check(const float* Al) {
  const float lntab[16] = {0.f, 0.6931472f, 1.0986123f, 1.3862944f, 1.6094379f,
                           1.7917595f, 1.9459101f, 2.0794415f, 2.1972246f, 2.3025851f,
                           2.3978953f, 2.4849066f, 2.5649494f, 2.6390573f, 2.7080502f,
                           2.7725887f};
  bool g = true;
  #pragma unroll
  for (int n = 0; n < NS; ++n)
    g = g && (fabsf(Al[n] - Al[0] - lntab[n]) <= 2e-3f);
  return g;
}

// packed dt6: s = bsv + w.t
__device__ __forceinline__ float dt6p(const v2f* w2, float bsv, float4 t0, float4 t1) {
  v2f acc = pk_mul(w2[0], mkv2(t0.x, t0.y));
  acc = pk_fma(w2[1], mkv2(t0.z, t0.w), acc);
  acc = pk_fma(w2[2], mkv2(t1.x, t1.y), acc);
  return bsv + acc.x + acc.y;
}

// packed powers: pw2[q] = {e^(2q+1), e^(2q+2)}, q=0..7
__device__ __forceinline__ void pw8p(float e, v2f* pw2) {
  float e2 = e * e;
  v2f ee2 = mkv2(e2, e2);
  pw2[0] = mkv2(e, e2);
  #pragma unroll
  for (int q = 1; q < 8; ++q) pw2[q] = pk_mul(pw2[q - 1], ee2);
}

__device__ __forceinline__ float dt6(const float* w, float bsv, float4 t0, float4 t1) {
  return bsv + w[0]*t0.x + w[1]*t0.y + w[2]*t0.z + w[3]*t0.w + w[4]*t1.x + w[5]*t1.y;
}

// ---------------- merged weight prep: WcatT[192][160], inpT[96][384], outpT[192][96]
__launch_bounds__(256)
__global__ void prep_weights(const float* __restrict__ xw, const float* __restrict__ ipw,
                             const float* __restrict__ opw, float* __restrict__ WcatT,
                             float* __restrict__ inpT, float* __restrict__ outpT) {
  int idx = blockIdx.x * 256 + threadIdx.x;
  if (idx < DI * XDS) {                          // WcatT
    int col = idx / XDS, j = idx % XDS;
    int k = j / 40, jj = j % 40;
    float v = 0.f;
    int src = -1;
    if (jj < 16)      src = k * 38 + 6 + jj;
    else if (jj < 32) src = k * 38 + 22 + (jj - 16);
    else if (jj < 38) src = k * 38 + (jj - 32);
    if (src >= 0) v = xw[(size_t)src * DI + col];
    WcatT[idx] = v;
    return;
  }
  idx -= DI * XDS;
  if (idx < 2 * DI * DM) {                       // inpT[c][r] = ipw[r][c]
    int r = idx / DM, c = idx % DM;
    inpT[(size_t)c * (2 * DI) + r] = ipw[idx];
    return;
  }
  idx -= 2 * DI * DM;
  if (idx < DM * DI) {                           // outpT[c][r] = opw[r][c]
    int r = idx / DI, c = idx % DI;
    outpT[(size_t)c * DM + r] = opw[idx];
  }
}

// ---------------- GEMM: C[M,NN] = A[M,KK] * BT[KK,NN]   (BT pre-transposed) ------
template <int NN, int KK, int TM, int KT>
__launch_bounds__(256)
__global__ void gemm_nt(const float* __restrict__ A, const float* __restrict__ BT,
                        float* __restrict__ C, int M) {
  constexpr int TN  = 64;
  constexpr int RPT = TM / 16;
  constexpr int SA  = KT + 4;
  constexpr int KQ  = KT / 4;
  __shared__ float As[TM][SA];
  __shared__ float Bs[KT][TN];
  const int t = threadIdx.x;
  const int row0 = blockIdx.y * TM;
  const int col0 = blockIdx.x * TN;
  const int tc = t & 15;
  const int tr = t >> 4;

  float acc[RPT][4];
  #pragma unroll
  for (int i = 0; i < RPT; ++i)
    { acc[i][0]=0.f; acc[i][1]=0.f; acc[i][2]=0.f; acc[i][3]=0.f; }

  for (int k0 = 0; k0 < KK; k0 += KT) {
    #pragma unroll 1
    for (int idx = t; idx < TM * KQ; idx += 256) {
      int r = idx / KQ, kq = idx % KQ;
      *(float4*)&As[r][kq * 4] =
          *(const float4*)&A[(size_t)(row0 + r) * KK + k0 + kq * 4];
    }
    #pragma unroll 1
    for (int idx = t; idx < KT * 16; idx += 256) {
      int kk = idx >> 4, cq = idx & 15;
      int col = col0 + cq * 4;
      float4 v = make_float4(0.f, 0.f, 0.f, 0.f);
      if (col < NN) v = *(const float4*)&BT[(size_t)(k0 + kk) * NN + col];
      *(float4*)&Bs[kk][cq * 4] = v;
    }
    __syncthreads();
    #pragma unroll 4
    for (int kk = 0; kk < KT; ++kk) {
      float4 bv = *(const float4*)&Bs[kk][tc * 4];
      #pragma unroll
      for (int i = 0; i < RPT; ++i) {
        float a = As[tr * RPT + i][kk];
        acc[i][0] += a * bv.x; acc[i][1] += a * bv.y;
        acc[i][2] += a * bv.z; acc[i][3] += a * bv.w;
      }
    }
    __syncthreads();
  }
  int c = col0 + tc * 4;
  if (c < NN) {
    #pragma unroll
    for (int i = 0; i < RPT; ++i) {
      size_t r0 = (size_t)(row0 + tr * RPT + i) * NN + c;
      *(float4*)&C[r0] = make_float4(acc[i][0], acc[i][1], acc[i][2], acc[i][3]);
    }
  }
}

// ---------------- depthwise 3x3 conv + bias + SiLU ----------------
__launch_bounds__(256)
__global__ void conv_silu(const float* __restrict__ xz, const float* __restrict__ cw,
                          const float* __restrict__ cb, float* __restrict__ xc) {
  int idx = blockIdx.x * 256 + threadIdx.x;
  int d = idx % DI;
  int p = (idx / DI) % LSEQ;
  int b = idx / (DI * LSEQ);
  int h = p >> 6, w = p & 63;
  float acc = cb[d];
  #pragma unroll
  for (int kh = 0; kh < 3; ++kh) {
    int hh = h + kh - 1;
    if ((unsigned)hh >= (unsigned)HS) continue;
    #pragma unroll
    for (int kw = 0; kw < 3; ++kw) {
      int ww = w + kw - 1;
      if ((unsigned)ww >= (unsigned)WSZ) continue;
      acc += xz[((size_t)b * LSEQ + (hh << 6) + ww) * (2 * DI) + d] * cw[d * 9 + kh * 3 + kw];
    }
  }
  xc[idx] = acc / (1.f + __expf(-acc));
}

// ---- scan phase 1: local scan + y_loc (packed fp32, pointer-walk) ---------------
__launch_bounds__(192)
__global__ void scan_phase1(const float* __restrict__ xc, const float* __restrict__ xdbl,
                            const float* __restrict__ Alog, const float* __restrict__ dtw,
                            const float* __restrict__ dtb,
                            float* __restrict__ hN, float* __restrict__ sumdB,
                            float* __restrict__ ypl) {
  const int d = threadIdx.x;
  const int ch = blockIdx.x, k = blockIdx.y, b = blockIdx.z;
  const int bk = b * KD + k;
  __shared__ float4 Bsh[CLEN * 10];         // per pos: B(0..3) C(4..7) dt(8,9)
  #pragma unroll 1
  for (int idx = d; idx < CLEN * 10; idx += 192) {
    int j = idx / 10, q = idx % 10;
    int p = pos_of(k, ch * CLEN + j);
    Bsh[idx] = *(const float4*)&xdbl[(size_t)(b * LSEQ + p) * XDS + k * 40 + q * 4];
  }
  float Al[NS];
  {
    const float4* Ap = (const float4*)&Alog[((size_t)k * DI + d) * NS];
    #pragma unroll
    for (int q = 0; q < 4; ++q) {
      float4 a = Ap[q];
      Al[q*4+0] = a.x; Al[q*4+1] = a.y; Al[q*4+2] = a.z; Al[q*4+3] = a.w;
    }
  }
  const bool geo = geo_check(Al);
  const float An0 = -__expf(Al[0]);
  float w[RK];
  #pragma unroll
  for (int r = 0; r < RK; ++r) w[r] = dtw[((size_t)k * DI + d) * RK + r];
  const float bsv = dtb[k * DI + d];
  v2f w2[3];
  w2[0] = mkv2(w[0], w[1]); w2[1] = mkv2(w[2], w[3]); w2[2] = mkv2(w[4], w[5]);
  __syncthreads();

  float sumd = 0.f;
  const int l0 = ch * CLEN;
  const int p0 = pos_of(k, l0);
  const long pstride = (long)pos_step(k) * DI;
  const float* xcp = xc + ((size_t)b * LSEQ + p0) * DI + d;
  float* youtp = ypl + ((size_t)bk * LSEQ + p0) * DI + d;
  v2f h2[8];
  #pragma unroll
  for (int q = 0; q < 8; ++q) h2[q] = mkv2(0.f, 0.f);
  if (geo) {
    #pragma unroll 2
    for (int j = 0; j < CLEN; ++j) {
      float4 t0 = Bsh[j * 10 + 8], t1 = Bsh[j * 10 + 9];
      float dl = softplus_f(dt6p(w2, bsv, t0, t1));
      float du = dl * (*xcp);
      v2f du2 = mkv2(du, du);
      v2f pw2[8];
      pw8p(__expf(dl * An0), pw2);
      v2f y2 = mkv2(0.f, 0.f);
      #pragma unroll
      for (int q = 0; q < 4; ++q) {
        float4 v  = Bsh[j * 10 + q];
        float4 c4 = Bsh[j * 10 + 4 + q];
        h2[2*q]   = pk_fma(pw2[2*q],   h2[2*q],   pk_mul(du2, mkv2(v.x, v.y)));
        y2 = pk_fma(h2[2*q],   mkv2(c4.x, c4.y), y2);
        h2[2*q+1] = pk_fma(pw2[2*q+1], h2[2*q+1], pk_mul(du2, mkv2(v.z, v.w)));
        y2 = pk_fma(h2[2*q+1], mkv2(c4.z, c4.w), y2);
      }
      sumd += dl;
      *youtp = y2.x + y2.y;
      xcp += pstride; youtp += pstride;
    }
  } else {
    float An[NS];
    #pragma unroll
    for (int n = 0; n < NS; ++n) An[n] = -__expf(Al[n]);
    float h[NS];
    #pragma unroll
    for (int n = 0; n < NS; ++n) h[n] = 0.f;
    #pragma unroll 1
    for (int j = 0; j < CLEN; ++j) {
      float4 t0 = Bsh[j * 10 + 8], t1 = Bsh[j * 10 + 9];
      float dl = softplus_f(dt6(w, bsv, t0, t1));
      float du = dl * (*xcp);
      float y = 0.f;
      #pragma unroll
      for (int q = 0; q < 4; ++q) {
        float4 v  = Bsh[j * 10 + q];
        float4 c4 = Bsh[j * 10 + 4 + q];
        h[q*4+0] = __expf(dl * An[q*4+0]) * h[q*4+0] + du * v.x; y += h[q*4+0] * c4.x;
        h[q*4+1] = __expf(dl * An[q*4+1]) * h[q*4+1] + du * v.y; y += h[q*4+1] * c4.y;
        h[q*4+2] = __expf(dl * An[q*4+2]) * h[q*4+2] + du * v.z; y += h[q*4+2] * c4.z;
        h[q*4+3] = __expf(dl * An[q*4+3]) * h[q*4+3] + du * v.w; y += h[q*4+3] * c4.w;
      }
      sumd += dl;
      *youtp = y;
      xcp += pstride; youtp += pstride;
    }
    #pragma unroll
    for (int q = 0; q < 8; ++q) h2[q] = mkv2(h[2*q], h[2*q+1]);
  }
  const size_t o = ((size_t)bk * NCH + ch) * DI + d;
  float4* Hp = (float4*)&hN[o * NS];
  #pragma unroll
  for (int q = 0; q < 4; ++q)
    Hp[q] = make_float4(h2[2*q].x, h2[2*q].y, h2[2*q+1].x, h2[2*q+1].y);
  sumdB[o] = sumd;
}

// ---- fused hierarchical combine: one block per (bk,d): 16 n x 16 groups --------
__launch_bounds__(256)
__global__ void combine_all(float* __restrict__ hN, const float* __restrict__ sumdB,
                            const float* __restrict__ Alog) {
  const int t = threadIdx.x;
  const int n = t & 15;
  const int g = t >> 4;
  const int d = blockIdx.x;
  const int k = blockIdx.y, b = blockIdx.z;
  const int bk = b * KD + k;
  const float An = -__expf(Alog[((size_t)k * DI + d) * NS + n]);
  __shared__ float Wl[GCH][NS], Tl[GCH][NS], Hl[GCH][NS];

  float wreg[GLEN], hreg[GLEN];
  float W = 1.f, T = 0.f;
  #pragma unroll
  for (int j = 0; j < GLEN; ++j) {
    const int c = g * GLEN + j;
    const size_t o = ((size_t)bk * NCH + c) * DI + d;
    float wv = __expf(An * sumdB[o]);
    float hv = hN[o * NS + n];
    wreg[j] = wv; hreg[j] = hv;
    T = hv + wv * T;
    W *= wv;
  }
  Wl[g][n] = W; Tl[g][n] = T;
  __syncthreads();
  if (g == 0) {
    float H = 0.f;
    #pragma unroll
    for (int g2 = 0; g2 < GCH; ++g2) {
      float Wv = Wl[g2][n], Tv = Tl[g2][n];
      Hl[g2][n] = H;
      H = Tv + Wv * H;
    }
  }
  __syncthreads();
  float e = Hl[g][n];
  #pragma unroll
  for (int j = 0; j < GLEN; ++j) {
    const int c = g * GLEN + j;
    const size_t o = ((size_t)bk * NCH + c) * DI + d;
    hN[o * NS + n] = e;
    e = hreg[j] + wreg[j] * e;
  }
}

// ---- scan correction (packed fp32, pointer-walk): ypl[p] += C.(h0*exp(An*cum)) --
__launch_bounds__(192)
__global__ void scan_corr(const float* __restrict__ xdbl, const float* __restrict__ Alog,
                          const float* __restrict__ dtw, const float* __restrict__ dtb,
                          const float* __restrict__ hin, float* __restrict__ ypl) {
  const int d = threadIdx.x;
  const int ch = blockIdx.x + 1;            // ch=0 has zero entry state
  const int k = blockIdx.y, b = blockIdx.z;
  const int bk = b * KD + k;
  __shared__ float4 Bsh[CLEN * 6];          // per pos: C(q4..7) dt(q8,q9)
  {
    int idx = d;                            // CLEN*6 == 192
    int j = idx / 6, q = idx % 6;
    int p = pos_of(k, ch * CLEN + j);
    Bsh[idx] = *(const float4*)&xdbl[(size_t)(b * LSEQ + p) * XDS + k * 40 + (q + 4) * 4];
  }
  float Al[NS];
  {
    const float4* Ap = (const float4*)&Alog[((size_t)k * DI + d) * NS];
    #pragma unroll
    for (int q = 0; q < 4; ++q) {
      float4 a = Ap[q];
      Al[q*4+0] = a.x; Al[q*4+1] = a.y; Al[q*4+2] = a.z; Al[q*4+3] = a.w;
    }
  }
  const bool geo = geo_check(Al);
  const float An0 = -__expf(Al[0]);
  float w[RK];
  #pragma unroll
  for (int r = 0; r < RK; ++r) w[r] = dtw[((size_t)k * DI + d) * RK + r];
  const float bsv = dtb[k * DI + d];
  v2f w2[3];
  w2[0] = mkv2(w[0], w[1]); w2[1] = mkv2(w[2], w[3]); w2[2] = mkv2(w[4], w[5]);

  v2f g2[8];                                // entry state h0
  {
    const size_t o = ((size_t)bk * NCH + ch) * DI + d;
    const float4* Hp = (const float4*)&hin[o * NS];
    #pragma unroll
    for (int q = 0; q < 4; ++q) {
      float4 v = Hp[q];
      g2[2*q]   = mkv2(v.x, v.y);
      g2[2*q+1] = mkv2(v.z, v.w);
    }
  }
  __syncthreads();
  const int l0 = ch * CLEN;
  const int p0 = pos_of(k, l0);
  const long pstride = (long)pos_step(k) * DI;
  float* youtp = ypl + ((size_t)bk * LSEQ + p0) * DI + d;
  float cum = 0.f;
  if (geo) {
    #pragma unroll 2
    for (int j = 0; j < CLEN; ++j) {
      float4 t0 = Bsh[j * 6 + 4], t1 = Bsh[j * 6 + 5];
      cum += softplus_f(dt6p(w2, bsv, t0, t1));
      v2f pw2[8];
      pw8p(__expf(cum * An0), pw2);
      v2f y2 = mkv2(0.f, 0.f);
      #pragma unroll
      for (int q = 0; q < 4; ++q) {
        float4 c4 = Bsh[j * 6 + q];
        y2 = pk_fma(pk_mul(pw2[2*q],   g2[2*q]),   mkv2(c4.x, c4.y), y2);
        y2 = pk_fma(pk_mul(pw2[2*q+1], g2[2*q+1]), mkv2(c4.z, c4.w), y2);
      }
      *youtp += y2.x + y2.y;
      youtp += pstride;
    }
  } else {
    float An[NS];
    #pragma unroll
    for (int n = 0; n < NS; ++n) An[n] = -__expf(Al[n]);
    #pragma unroll 1
    for (int j = 0; j < CLEN; ++j) {
      float4 t0 = Bsh[j * 6 + 4], t1 = Bsh[j * 6 + 5];
      cum += softplus_f(dt6(w, bsv, t0, t1));
      float y = 0.f;
      #pragma unroll
      for (int q = 0; q < 4; ++q) {
        float4 c4 = Bsh[j * 6 + q];
        y += (__expf(An[q*4+0] * cum) * g2[2*q].x)   * c4.x;
        y += (__expf(An[q*4+1] * cum) * g2[2*q].y)   * c4.y;
        y += (__expf(An[q*4+2] * cum) * g2[2*q+1].x) * c4.z;
        y += (__expf(An[q*4+3] * cum) * g2[2*q+1].y) * c4.w;
      }
      *youtp += y;
      youtp += pstride;
    }
  }
}

// -------- 4-plane merge (Ds term) + LayerNorm + SiLU gate ----------------
__launch_bounds__(192)
__global__ void fuse_ln(const float* __restrict__ ypl, const float* __restrict__ xc,
                        const float* __restrict__ Ds, const float* __restrict__ xz,
                        const float* __restrict__ lnw, const float* __restrict__ lnb,
                        float* __restrict__ ymul) {
  const int row = blockIdx.x;           // b*L + p
  const int b = row >> 12;
  const size_t pd = (size_t)row * DI + threadIdx.x;
  const int d = threadIdx.x;
  constexpr size_t PL = (size_t)LSEQ * DI;
  float u = xc[pd];
  float sDs = Ds[d] + Ds[DI + d] + Ds[2 * DI + d] + Ds[3 * DI + d];
  const size_t base = (size_t)(b * KD) * PL + pd - (size_t)b * PL;
  float y = ypl[base] + ypl[base + PL] + ypl[base + 2 * PL] + ypl[base + 3 * PL] + sDs * u;
  float s1 = y, s2 = y * y;
  #pragma unroll
  for (int off = 32; off; off >>= 1) {
    s1 += __shfl_xor(s1, off);
    s2 += __shfl_xor(s2, off);
  }
  __shared__ float r1[3], r2[3];
  int wid = d >> 6;
  if ((d & 63) == 0) { r1[wid] = s1; r2[wid] = s2; }
  __syncthreads();
  float S1 = r1[0] + r1[1] + r1[2];
  float S2 = r2[0] + r2[1] + r2[2];
  float mu = S1 * (1.f / DI);
  float var = S2 * (1.f / DI) - mu * mu;
  float yn = (y - mu) * rsqrtf(var + 1e-5f) * lnw[d] + lnb[d];
  float zv = xz[(size_t)row * (2 * DI) + DI + d];
  float g = zv / (1.f + __expf(-zv));
  ymul[pd] = yn * g;
}

// ---------------- launcher ----------------
extern "C" void kernel_launch(void* const* d_in, const int* in_sizes, int n_in,
                              void* d_out, int out_size, void* d_ws, size_t ws_size,
                              hipStream_t stream) {
  (void)in_sizes; (void)n_in; (void)out_size; (void)ws_size;
  const float* x          = (const float*)d_in[0];
  const float* in_proj_w  = (const float*)d_in[1];
  const float* conv_w     = (const float*)d_in[2];
  const float* conv_b     = (const float*)d_in[3];
  const float* x_proj_w   = (const float*)d_in[4];
  const float* dt_w       = (const float*)d_in[5];
  const float* dt_b       = (const float*)d_in[6];
  const float* A_logs     = (const float*)d_in[7];
  const float* Ds         = (const float*)d_in[8];
  const float* ln_w       = (const float*)d_in[9];
  const float* ln_b       = (const float*)d_in[10];
  const float* out_proj_w = (const float*)d_in[11];
  float* out = (float*)d_out;
  float* ws  = (float*)d_ws;

  constexpr size_t SZ_XZ    = (size_t)BATCH * LSEQ * 2 * DI;
  constexpr size_t SZ_XC    = (size_t)BATCH * LSEQ * DI;
  constexpr size_t SZ_XD    = (size_t)BATCH * LSEQ * XDS;
  constexpr size_t SZ_HN    = (size_t)BATCH * KD * NCH * DI * NS;   // 25 MB
  constexpr size_t SZ_SUMD  = (size_t)BATCH * KD * NCH * DI;
  constexpr size_t SZ_YPL   = (size_t)BATCH * KD * LSEQ * DI;

  float* xz    = ws;
  float* xc    = xz + SZ_XZ;
  float* xdbl  = xc + SZ_XC;
  float* hN    = xdbl + SZ_XD;
  float* sumd  = hN + SZ_HN;
  float* ypl   = sumd + SZ_SUMD;
  float* WcatT = ypl + SZ_YPL;
  float* inpT  = WcatT + (size_t)DI * XDS;
  float* outpT = inpT + (size_t)DM * 2 * DI;
  float* ymul  = hN;    // hN dead after scan_corr; reuse for LN output

  const int M = BATCH * LSEQ;  // 16384
  const int PREP = DI * XDS + 2 * DI * DM + DM * DI;

  // 0. weight prep (merged)
  prep_weights<<<(PREP + 255) / 256, 256, 0, stream>>>(x_proj_w, in_proj_w, out_proj_w,
                                                       WcatT, inpT, outpT);
  // 1. in_proj
  gemm_nt<2 * DI, DM, 64, 96><<<dim3(6, M / 64), 256, 0, stream>>>(x, inpT, xz, M);
  // 2. depthwise conv + SiLU -> xc
  conv_silu<<<(BATCH * LSEQ * DI) / 256, 256, 0, stream>>>(xz, conv_w, conv_b, xc);
  // 3. x_proj all directions: xdbl[M,160]
  gemm_nt<XDS, DI, 64, 96><<<dim3(3, M / 64), 256, 0, stream>>>(xc, WcatT, xdbl, M);
  // 4. scan phase 1: local scan + y_loc -> planes (packed fp32)
  scan_phase1<<<dim3(NCH, KD, BATCH), 192, 0, stream>>>(xc, xdbl, A_logs, dt_w, dt_b,
                                                        hN, sumd, ypl);
  // 5. fused hierarchical combine (hN -> entry states, in place)
  combine_all<<<dim3(DI, KD, BATCH), 256, 0, stream>>>(hN, sumd, A_logs);
  // 6. correction: ypl += C . (h0 * exp(An*cumDelta))  (packed fp32)
  scan_corr<<<dim3(NCH - 1, KD, BATCH), 192, 0, stream>>>(xdbl, A_logs, dt_w, dt_b,
                                                          hN, ypl);
  // 7. merge 4 planes + LN + gate -> ymul (aliases hN)
  fuse_ln<<<M, DI, 0, stream>>>(ypl, xc, Ds, xz, ln_w, ln_b, ymul);
  // 8. out_proj
  gemm_nt<DM, DI, 64, 96><<<dim3(2, M / 64), 256, 0, stream>>>(ymul, outpT, out, M);
}